// Round 4
// baseline (287.683 us; speedup 1.0000x reference)
//
#include <hip/hip_runtime.h>
#include <math.h>

#define NUM_TOK 2048
#define HDIM 1024
#define IDIM 2048
#define NEXP 8
#define MAX_ROWS 5120
#define NTM 40

typedef __attribute__((ext_vector_type(8))) short bf16x8;
typedef __attribute__((ext_vector_type(4))) float f32x4;

// ---- workspace offsets (bytes) ----
#define OFF_IDX   0u
#define OFF_RW    16384u
#define OFF_CNT   32768u
#define OFF_SEG   32832u
#define OFF_ROWS  33024u
#define OFF_POS   53504u
#define OFF_XB    131072u
#define OFF_W1T   8388608u
#define OFF_W3T   41943040u
#define OFF_W2T   75497472u
#define OFF_ACT   109051904u
#define OFF_SO    8388608u   /* aliases W1T (dead once gemm2 runs) */

__device__ __forceinline__ unsigned short f2bf(float f) {
  union { float f; unsigned u; } v; v.f = f;
  unsigned r = v.u + 0x7FFF + ((v.u >> 16) & 1);   // RNE
  return (unsigned short)(r >> 16);
}

__device__ __forceinline__ void gld16(const void* g, void* l) {
  __builtin_amdgcn_global_load_lds(
      (const __attribute__((address_space(1))) void*)g,
      (__attribute__((address_space(3))) void*)l, 16, 0, 0);
}

__global__ void k_init(int* __restrict__ cnt, int* __restrict__ rowsv) {
  const int i = blockIdx.x * blockDim.x + threadIdx.x;
  if (i < 16) cnt[i] = 0;
  if (i < MAX_ROWS) rowsv[i] = -1;
}

// fused transpose + fp32->bf16 for all three weights.
// z 0..7: W1 (H,I)->(I,H); 8..15: W3; 16..23: W2 (I,H)->(H,I)
__global__ void k_wtall(const float* __restrict__ W1, const float* __restrict__ W3,
                        const float* __restrict__ W2,
                        unsigned short* __restrict__ W1T,
                        unsigned short* __restrict__ W3T,
                        unsigned short* __restrict__ W2T) {
  __shared__ __align__(16) unsigned short tile[64 * 72];
  const int z = blockIdx.z;
  const float* src; unsigned short* dst; int R, C, eidx;
  if (z < 8)       { src = W1; dst = W1T; R = HDIM; C = IDIM; eidx = z; }
  else if (z < 16) { src = W3; dst = W3T; R = HDIM; C = IDIM; eidx = z - 8; }
  else             { src = W2; dst = W2T; R = IDIM; C = HDIM; eidx = z - 16; }
  const int r0 = blockIdx.y * 64, c0 = blockIdx.x * 64;
  if (r0 >= R || c0 >= C) return;
  const int tid = threadIdx.x;
  const size_t base = (size_t)eidx * R * C;
  const int c4 = (tid & 15) * 4;
#pragma unroll
  for (int j = 0; j < 4; ++j) {
    const int r = (tid >> 4) + j * 16;
    const float4 v = *(const float4*)(src + base + (size_t)(r0 + r) * C + c0 + c4);
    tile[(c4 + 0) * 72 + r] = f2bf(v.x);
    tile[(c4 + 1) * 72 + r] = f2bf(v.y);
    tile[(c4 + 2) * 72 + r] = f2bf(v.z);
    tile[(c4 + 3) * 72 + r] = f2bf(v.w);
  }
  __syncthreads();
  const int r8 = (tid & 7) * 8;
#pragma unroll
  for (int j = 0; j < 2; ++j) {
    const int c = (tid >> 3) + j * 32;
    const uint4 d = *(const uint4*)&tile[c * 72 + r8];
    *(uint4*)(dst + base + (size_t)(c0 + c) * R + r0 + r8) = d;
  }
}

__global__ void k_router(const float* __restrict__ x, const float* __restrict__ wg,
                         unsigned short* __restrict__ xb,
                         int* __restrict__ idx, float* __restrict__ rw,
                         int* __restrict__ cnt) {
  const int wave = threadIdx.x >> 6, lane = threadIdx.x & 63;
  const int t = blockIdx.x * 4 + wave;
  const float2* __restrict__ xr = (const float2*)(x + (size_t)t * HDIM);
  unsigned* __restrict__ xbr = (unsigned*)(xb + (size_t)t * HDIM);
  float acc[8];
#pragma unroll
  for (int q = 0; q < 8; ++q) acc[q] = 0.f;
#pragma unroll
  for (int j = 0; j < 8; ++j) {
    const int h2 = lane + (j << 6);
    const float2 v = xr[h2];
    const float* wrow = wg + (size_t)h2 * 16;
    const float4 a0 = *(const float4*)(wrow);
    const float4 a1 = *(const float4*)(wrow + 4);
    const float4 b0 = *(const float4*)(wrow + 8);
    const float4 b1 = *(const float4*)(wrow + 12);
    acc[0] = fmaf(v.x, a0.x, fmaf(v.y, b0.x, acc[0]));
    acc[1] = fmaf(v.x, a0.y, fmaf(v.y, b0.y, acc[1]));
    acc[2] = fmaf(v.x, a0.z, fmaf(v.y, b0.z, acc[2]));
    acc[3] = fmaf(v.x, a0.w, fmaf(v.y, b0.w, acc[3]));
    acc[4] = fmaf(v.x, a1.x, fmaf(v.y, b1.x, acc[4]));
    acc[5] = fmaf(v.x, a1.y, fmaf(v.y, b1.y, acc[5]));
    acc[6] = fmaf(v.x, a1.z, fmaf(v.y, b1.z, acc[6]));
    acc[7] = fmaf(v.x, a1.w, fmaf(v.y, b1.w, acc[7]));
    xbr[h2] = (unsigned)f2bf(v.x) | ((unsigned)f2bf(v.y) << 16);
  }
#pragma unroll
  for (int q = 0; q < 8; ++q) {
#pragma unroll
    for (int off = 32; off >= 1; off >>= 1)
      acc[q] += __shfl_xor(acc[q], off, 64);
  }
  if (lane == 0) {
    int i0 = 0; float v0 = acc[0];
#pragma unroll
    for (int q = 1; q < 8; ++q)
      if (acc[q] > v0) { v0 = acc[q]; i0 = q; }
    int i1 = -1; float v1 = -3.4e38f;
#pragma unroll
    for (int q = 0; q < 8; ++q)
      if (q != i0 && acc[q] > v1) { v1 = acc[q]; i1 = q; }
    const float e1 = expf(v1 - v0);
    const float inv = 1.f / (1.f + e1);
    idx[2 * t] = i0; idx[2 * t + 1] = i1;
    rw[2 * t] = inv; rw[2 * t + 1] = e1 * inv;
    atomicAdd(&cnt[i0], 1);
    atomicAdd(&cnt[i1], 1);
  }
}

__global__ void k_seg(const int* __restrict__ cnt, int* __restrict__ seg) {
  int s = 0;
  for (int q = 0; q < NEXP; ++q) {
    seg[q] = s;
    s += ((cnt[q] + 127) / 128) * 128;
  }
  seg[NEXP] = s;
}

__global__ void k_scatter(const int* __restrict__ idx, const int* __restrict__ seg,
                          int* __restrict__ cursor, int* __restrict__ rowsv,
                          int* __restrict__ pos) {
  const int t = blockIdx.x * blockDim.x + threadIdx.x;
  if (t < NUM_TOK) {
#pragma unroll
    for (int k = 0; k < 2; ++k) {
      const int slot = 2 * t + k;
      const int e = idx[slot];
      const int p = atomicAdd(&cursor[e], 1);
      const int rr = seg[e] + p;
      rowsv[rr] = slot;
      pos[slot] = rr;
    }
  }
}

// grouped GEMM1: act = silu(x@W1) * (x@W3).
// BM=128, BN=128 (cols of BOTH W1 and W3), BK=32, 4 waves.
// Wave tile: 128 M x (32 W1-cols + 32 W3-cols): 8 m-frags x 4 n-frags,
// acc 128 VGPR, 32 MFMA vs 12 ds_read_b128 per K-step.
__launch_bounds__(256, 2)
__global__ void k_gemm1(const unsigned short* __restrict__ xb,
                        const unsigned short* __restrict__ W1T,
                        const unsigned short* __restrict__ W3T,
                        const int* __restrict__ seg, const int* __restrict__ rowsv,
                        unsigned short* __restrict__ act) {
  __shared__ __align__(16) unsigned short As[2][128 * 32];
  __shared__ __align__(16) unsigned short Bs[2][256 * 32];
  const int tid = threadIdx.x;
  const int w = tid >> 6, l = tid & 63;
  const int m0 = blockIdx.y * 128;
  const int total = seg[NEXP];
  if (m0 >= total) return;
  int e = 0;
#pragma unroll
  for (int q = 1; q < NEXP; ++q) if (m0 >= seg[q]) e = q;
  const int n0 = blockIdx.x * 128;

  const int swz = ((tid & 3) ^ ((tid >> 3) & 3)) * 8;  // swizzled source col (elems)
  // A staging: 2 issues, row = q*64 + (tid>>2)
  size_t aOff[2];
#pragma unroll
  for (int q = 0; q < 2; ++q) {
    const int r = rowsv[m0 + q * 64 + (tid >> 2)];
    const int tk = (r < 0) ? 0 : (r >> 1);
    aOff[q] = (size_t)tk * HDIM + swz;
  }
  // B staging: 4 issues; q<2 -> W1T rows n0+q*64.., q>=2 -> W3T rows n0+(q-2)*64..
  size_t bOff[4];
#pragma unroll
  for (int q = 0; q < 4; ++q)
    bOff[q] = ((size_t)e * IDIM + n0 + (q & 1) * 64 + (tid >> 2)) * HDIM + swz;

  f32x4 acc[8][4];
#pragma unroll
  for (int mf = 0; mf < 8; ++mf)
#pragma unroll
    for (int nf = 0; nf < 4; ++nf) acc[mf][nf] = (f32x4)0.f;

  auto stage = [&](int buf, int k0) {
#pragma unroll
    for (int q = 0; q < 2; ++q)
      gld16(xb + aOff[q] + k0, &As[buf][(q * 64 + (tid >> 2)) * 32 + (tid & 3) * 8]);
#pragma unroll
    for (int q = 0; q < 4; ++q)
      gld16(((q < 2) ? W1T : W3T) + bOff[q] + k0,
            &Bs[buf][(q * 64 + (tid >> 2)) * 32 + (tid & 3) * 8]);
  };

  stage(0, 0);
  __syncthreads();
  const int rslot = ((l >> 4) ^ ((l >> 1) & 3)) * 8;  // swizzled read slot (elems)
  for (int t = 0; t < HDIM / 32; ++t) {
    const int cur = t & 1;
    if (t + 1 < HDIM / 32) stage(cur ^ 1, (t + 1) * 32);
    bf16x8 a[8], b[4];
#pragma unroll
    for (int mf = 0; mf < 8; ++mf)
      a[mf] = *(const bf16x8*)&As[cur][(mf * 16 + (l & 15)) * 32 + rslot];
#pragma unroll
    for (int nf = 0; nf < 4; ++nf) {
      const int brow = ((nf >= 2) ? 128 : 0) + w * 32 + (nf & 1) * 16 + (l & 15);
      b[nf] = *(const bf16x8*)&Bs[cur][brow * 32 + rslot];
    }
#pragma unroll
    for (int mf = 0; mf < 8; ++mf)
#pragma unroll
      for (int nf = 0; nf < 4; ++nf)
        acc[mf][nf] = __builtin_amdgcn_mfma_f32_16x16x32_bf16(a[mf], b[nf], acc[mf][nf], 0, 0, 0);
    __syncthreads();
  }
  // epilogue: silu(up)*gate; up = acc[mf][0..1], gate = acc[mf][2..3]
  const int rsub = (l >> 4) * 4;
  const int cb = n0 + w * 32 + (l & 15);
#pragma unroll
  for (int mf = 0; mf < 8; ++mf)
#pragma unroll
    for (int nf = 0; nf < 2; ++nf) {
      const f32x4 up = acc[mf][nf];
      const f32x4 gt = acc[mf][nf + 2];
#pragma unroll
      for (int r = 0; r < 4; ++r) {
        const float u = up[r];
        const float s = (u / (1.f + expf(-u))) * gt[r];
        act[(size_t)(m0 + mf * 16 + rsub + r) * IDIM + cb + nf * 16] = f2bf(s);
      }
    }
}

// grouped GEMM2: so[row][h] = act[row] @ W2T[e] (fp32 partials).
// BM=128, BN=128, BK=32, 2 waves; wave tile 64 M x 128 N (4 m-frags x 8 n-frags).
__launch_bounds__(128, 2)
__global__ void k_gemm2(const unsigned short* __restrict__ act,
                        const unsigned short* __restrict__ W2T,
                        const int* __restrict__ seg,
                        float* __restrict__ so) {
  __shared__ __align__(16) unsigned short As[2][128 * 32];
  __shared__ __align__(16) unsigned short Bs[2][128 * 32];
  const int tid = threadIdx.x;
  const int w = tid >> 6, l = tid & 63;
  const int m0 = blockIdx.y * 128;
  const int total = seg[NEXP];
  if (m0 >= total) return;
  int e = 0;
#pragma unroll
  for (int q = 1; q < NEXP; ++q) if (m0 >= seg[q]) e = q;
  const int n0 = blockIdx.x * 128;
  const int swz = ((tid & 3) ^ ((tid >> 3) & 3)) * 8;
  size_t aOff[4], bOff[4];
#pragma unroll
  for (int q = 0; q < 4; ++q) {
    aOff[q] = (size_t)(m0 + q * 32 + (tid >> 2)) * IDIM + swz;
    bOff[q] = ((size_t)e * HDIM + n0 + q * 32 + (tid >> 2)) * IDIM + swz;
  }

  f32x4 acc[4][8];
#pragma unroll
  for (int mf = 0; mf < 4; ++mf)
#pragma unroll
    for (int nf = 0; nf < 8; ++nf) acc[mf][nf] = (f32x4)0.f;

  auto stage = [&](int buf, int k0) {
#pragma unroll
    for (int q = 0; q < 4; ++q) {
      gld16(act + aOff[q] + k0, &As[buf][(q * 32 + (tid >> 2)) * 32 + (tid & 3) * 8]);
      gld16(W2T + bOff[q] + k0, &Bs[buf][(q * 32 + (tid >> 2)) * 32 + (tid & 3) * 8]);
    }
  };

  stage(0, 0);
  __syncthreads();
  const int rslot = ((l >> 4) ^ ((l >> 1) & 3)) * 8;
  for (int t = 0; t < IDIM / 32; ++t) {
    const int cur = t & 1;
    if (t + 1 < IDIM / 32) stage(cur ^ 1, (t + 1) * 32);
    bf16x8 a[4], b[8];
#pragma unroll
    for (int mf = 0; mf < 4; ++mf)
      a[mf] = *(const bf16x8*)&As[cur][(w * 64 + mf * 16 + (l & 15)) * 32 + rslot];
#pragma unroll
    for (int nf = 0; nf < 8; ++nf)
      b[nf] = *(const bf16x8*)&Bs[cur][(nf * 16 + (l & 15)) * 32 + rslot];
#pragma unroll
    for (int mf = 0; mf < 4; ++mf)
#pragma unroll
      for (int nf = 0; nf < 8; ++nf)
        acc[mf][nf] = __builtin_amdgcn_mfma_f32_16x16x32_bf16(a[mf], b[nf], acc[mf][nf], 0, 0, 0);
    __syncthreads();
  }
  const int rsub = (l >> 4) * 4;
#pragma unroll
  for (int mf = 0; mf < 4; ++mf)
#pragma unroll
    for (int nf = 0; nf < 8; ++nf)
#pragma unroll
      for (int r = 0; r < 4; ++r)
        so[(size_t)(m0 + w * 64 + mf * 16 + rsub + r) * HDIM + n0 + nf * 16 + (l & 15)] =
            acc[mf][nf][r];
}

__global__ void k_combine(const float* __restrict__ so, const int* __restrict__ pos,
                          const float* __restrict__ rw, float* __restrict__ out) {
  const int t = blockIdx.x, i = threadIdx.x;
  const int p0 = pos[2 * t], p1 = pos[2 * t + 1];
  const float w0 = rw[2 * t], w1 = rw[2 * t + 1];
  const float4 a = ((const float4*)(so + (size_t)p0 * HDIM))[i];
  const float4 b = ((const float4*)(so + (size_t)p1 * HDIM))[i];
  float4 o;
  o.x = w0 * a.x + w1 * b.x;
  o.y = w0 * a.y + w1 * b.y;
  o.z = w0 * a.z + w1 * b.z;
  o.w = w0 * a.w + w1 * b.w;
  ((float4*)(out + (size_t)t * HDIM))[i] = o;
}

extern "C" void kernel_launch(void* const* d_in, const int* in_sizes, int n_in,
                              void* d_out, int out_size, void* d_ws, size_t ws_size,
                              hipStream_t stream) {
  const float* x  = (const float*)d_in[0];
  const float* Wg = (const float*)d_in[1];
  const float* W1 = (const float*)d_in[2];
  const float* W2 = (const float*)d_in[3];   // (E, I, H)
  const float* W3 = (const float*)d_in[4];   // (E, H, I)
  float* out = (float*)d_out;
  char* ws = (char*)d_ws;
  int*   idx  = (int*)(ws + OFF_IDX);
  float* rw   = (float*)(ws + OFF_RW);
  int*   cnt  = (int*)(ws + OFF_CNT);
  int*   seg  = (int*)(ws + OFF_SEG);
  int*   rowsv= (int*)(ws + OFF_ROWS);
  int*   pos  = (int*)(ws + OFF_POS);
  unsigned short* xb  = (unsigned short*)(ws + OFF_XB);
  unsigned short* W1T = (unsigned short*)(ws + OFF_W1T);
  unsigned short* W3T = (unsigned short*)(ws + OFF_W3T);
  unsigned short* W2T = (unsigned short*)(ws + OFF_W2T);
  unsigned short* act = (unsigned short*)(ws + OFF_ACT);
  float* so = (float*)(ws + OFF_SO);

  k_init<<<20, 256, 0, stream>>>(cnt, rowsv);
  k_wtall<<<dim3(32, 32, 24), 256, 0, stream>>>(W1, W3, W2, W1T, W3T, W2T);
  k_router<<<NUM_TOK / 4, 256, 0, stream>>>(x, Wg, xb, idx, rw, cnt);
  k_seg<<<1, 1, 0, stream>>>(cnt, seg);
  k_scatter<<<NUM_TOK / 256, 256, 0, stream>>>(idx, seg, cnt + 8, rowsv, pos);
  k_gemm1<<<dim3(IDIM / 128, NTM), 256, 0, stream>>>(xb, W1T, W3T, seg, rowsv, act);
  k_gemm2<<<dim3(HDIM / 128, NTM), 128, 0, stream>>>(act, W2T, seg, so);
  k_combine<<<NUM_TOK, 256, 0, stream>>>(so, pos, rw, out);
}

// Round 5
// 252.393 us; speedup vs baseline: 1.1398x; 1.1398x over previous
//
#include <hip/hip_runtime.h>
#include <math.h>

#define NUM_TOK 2048
#define HDIM 1024
#define IDIM 2048
#define NEXP 8
#define MAX_ROWS 5120
#define NTM 40

typedef __attribute__((ext_vector_type(8))) short bf16x8;
typedef __attribute__((ext_vector_type(4))) float f32x4;

// ---- workspace offsets (bytes) ----
#define OFF_IDX   0u
#define OFF_RW    16384u
#define OFF_CNT   32768u
#define OFF_SEG   32832u
#define OFF_ROWS  33024u
#define OFF_POS   53504u
#define OFF_XB    131072u
#define OFF_W1T   8388608u
#define OFF_W3T   41943040u
#define OFF_W2T   75497472u
#define OFF_ACT   109051904u
#define OFF_SO    8388608u   /* aliases W1T (dead once gemm2 runs) */

__device__ __forceinline__ unsigned short f2bf(float f) {
  union { float f; unsigned u; } v; v.f = f;
  unsigned r = v.u + 0x7FFF + ((v.u >> 16) & 1);   // RNE
  return (unsigned short)(r >> 16);
}

__device__ __forceinline__ void gld16(const void* g, void* l) {
  __builtin_amdgcn_global_load_lds(
      (const __attribute__((address_space(1))) void*)g,
      (__attribute__((address_space(3))) void*)l, 16, 0, 0);
}

__global__ void k_init(int* __restrict__ cnt, int* __restrict__ rowsv) {
  const int i = blockIdx.x * blockDim.x + threadIdx.x;
  if (i < 16) cnt[i] = 0;
  if (i < MAX_ROWS) rowsv[i] = -1;
}

// fused transpose + fp32->bf16 for all three weights.
// z 0..7: W1 (H,I)->(I,H); 8..15: W3; 16..23: W2 (I,H)->(H,I)
__global__ void k_wtall(const float* __restrict__ W1, const float* __restrict__ W3,
                        const float* __restrict__ W2,
                        unsigned short* __restrict__ W1T,
                        unsigned short* __restrict__ W3T,
                        unsigned short* __restrict__ W2T) {
  __shared__ __align__(16) unsigned short tile[64 * 72];
  const int z = blockIdx.z;
  const float* src; unsigned short* dst; int R, C, eidx;
  if (z < 8)       { src = W1; dst = W1T; R = HDIM; C = IDIM; eidx = z; }
  else if (z < 16) { src = W3; dst = W3T; R = HDIM; C = IDIM; eidx = z - 8; }
  else             { src = W2; dst = W2T; R = IDIM; C = HDIM; eidx = z - 16; }
  const int r0 = blockIdx.y * 64, c0 = blockIdx.x * 64;
  if (r0 >= R || c0 >= C) return;
  const int tid = threadIdx.x;
  const size_t base = (size_t)eidx * R * C;
  const int c4 = (tid & 15) * 4;
#pragma unroll
  for (int j = 0; j < 4; ++j) {
    const int r = (tid >> 4) + j * 16;
    const float4 v = *(const float4*)(src + base + (size_t)(r0 + r) * C + c0 + c4);
    tile[(c4 + 0) * 72 + r] = f2bf(v.x);
    tile[(c4 + 1) * 72 + r] = f2bf(v.y);
    tile[(c4 + 2) * 72 + r] = f2bf(v.z);
    tile[(c4 + 3) * 72 + r] = f2bf(v.w);
  }
  __syncthreads();
  const int r8 = (tid & 7) * 8;
#pragma unroll
  for (int j = 0; j < 2; ++j) {
    const int c = (tid >> 3) + j * 32;
    const uint4 d = *(const uint4*)&tile[c * 72 + r8];
    *(uint4*)(dst + base + (size_t)(c0 + c) * R + r0 + r8) = d;
  }
}

__global__ void k_router(const float* __restrict__ x, const float* __restrict__ wg,
                         unsigned short* __restrict__ xb,
                         int* __restrict__ idx, float* __restrict__ rw,
                         int* __restrict__ cnt) {
  const int wave = threadIdx.x >> 6, lane = threadIdx.x & 63;
  const int t = blockIdx.x * 4 + wave;
  const float2* __restrict__ xr = (const float2*)(x + (size_t)t * HDIM);
  unsigned* __restrict__ xbr = (unsigned*)(xb + (size_t)t * HDIM);
  float acc[8];
#pragma unroll
  for (int q = 0; q < 8; ++q) acc[q] = 0.f;
#pragma unroll
  for (int j = 0; j < 8; ++j) {
    const int h2 = lane + (j << 6);
    const float2 v = xr[h2];
    const float* wrow = wg + (size_t)h2 * 16;
    const float4 a0 = *(const float4*)(wrow);
    const float4 a1 = *(const float4*)(wrow + 4);
    const float4 b0 = *(const float4*)(wrow + 8);
    const float4 b1 = *(const float4*)(wrow + 12);
    acc[0] = fmaf(v.x, a0.x, fmaf(v.y, b0.x, acc[0]));
    acc[1] = fmaf(v.x, a0.y, fmaf(v.y, b0.y, acc[1]));
    acc[2] = fmaf(v.x, a0.z, fmaf(v.y, b0.z, acc[2]));
    acc[3] = fmaf(v.x, a0.w, fmaf(v.y, b0.w, acc[3]));
    acc[4] = fmaf(v.x, a1.x, fmaf(v.y, b1.x, acc[4]));
    acc[5] = fmaf(v.x, a1.y, fmaf(v.y, b1.y, acc[5]));
    acc[6] = fmaf(v.x, a1.z, fmaf(v.y, b1.z, acc[6]));
    acc[7] = fmaf(v.x, a1.w, fmaf(v.y, b1.w, acc[7]));
    xbr[h2] = (unsigned)f2bf(v.x) | ((unsigned)f2bf(v.y) << 16);
  }
#pragma unroll
  for (int q = 0; q < 8; ++q) {
#pragma unroll
    for (int off = 32; off >= 1; off >>= 1)
      acc[q] += __shfl_xor(acc[q], off, 64);
  }
  if (lane == 0) {
    int i0 = 0; float v0 = acc[0];
#pragma unroll
    for (int q = 1; q < 8; ++q)
      if (acc[q] > v0) { v0 = acc[q]; i0 = q; }
    int i1 = -1; float v1 = -3.4e38f;
#pragma unroll
    for (int q = 0; q < 8; ++q)
      if (q != i0 && acc[q] > v1) { v1 = acc[q]; i1 = q; }
    const float e1 = expf(v1 - v0);
    const float inv = 1.f / (1.f + e1);
    idx[2 * t] = i0; idx[2 * t + 1] = i1;
    rw[2 * t] = inv; rw[2 * t + 1] = e1 * inv;
    atomicAdd(&cnt[i0], 1);
    atomicAdd(&cnt[i1], 1);
  }
}

__global__ void k_seg(const int* __restrict__ cnt, int* __restrict__ seg) {
  int s = 0;
  for (int q = 0; q < NEXP; ++q) {
    seg[q] = s;
    s += ((cnt[q] + 127) / 128) * 128;
  }
  seg[NEXP] = s;
}

__global__ void k_scatter(const int* __restrict__ idx, const int* __restrict__ seg,
                          int* __restrict__ cursor, int* __restrict__ rowsv,
                          int* __restrict__ pos) {
  const int t = blockIdx.x * blockDim.x + threadIdx.x;
  if (t < NUM_TOK) {
#pragma unroll
    for (int k = 0; k < 2; ++k) {
      const int slot = 2 * t + k;
      const int e = idx[slot];
      const int p = atomicAdd(&cursor[e], 1);
      const int rr = seg[e] + p;
      rowsv[rr] = slot;
      pos[slot] = rr;
    }
  }
}

// grouped GEMM1: act = silu(x@W1) * (x@W3); B-tile = 64 W1T rows + 64 W3T rows.
// (R3-proven config: BM=128, BN=64, 4 waves, wave tile 32x64+64, acc[2][8].)
__launch_bounds__(256, 2)
__global__ void k_gemm1(const unsigned short* __restrict__ xb,
                        const unsigned short* __restrict__ W1T,
                        const unsigned short* __restrict__ W3T,
                        const int* __restrict__ seg, const int* __restrict__ rowsv,
                        unsigned short* __restrict__ act) {
  __shared__ __align__(16) unsigned short As[2][128 * 32];
  __shared__ __align__(16) unsigned short Bs[2][128 * 32];
  const int tid = threadIdx.x;
  const int w = tid >> 6, l = tid & 63;
  const int m0 = blockIdx.y * 128;
  const int total = seg[NEXP];
  if (m0 >= total) return;
  int e = 0;
#pragma unroll
  for (int q = 1; q < NEXP; ++q) if (m0 >= seg[q]) e = q;
  const int n0 = blockIdx.x * 64;

  const int swzst = ((l & 3) ^ ((l >> 3) & 3)) * 8;   // staging source column (elems)
  size_t aOff[2], bOff[2];
#pragma unroll
  for (int q = 0; q < 2; ++q) {
    const int r = rowsv[m0 + w * 32 + q * 16 + (l >> 2)];
    const int tk = (r < 0) ? 0 : (r >> 1);
    aOff[q] = (size_t)tk * HDIM + swzst;
    bOff[q] = ((size_t)e * IDIM + n0 + (w & 1) * 32 + q * 16 + (l >> 2)) * HDIM + swzst;
  }
  const unsigned short* __restrict__ WT = (w < 2) ? W1T : W3T;

  f32x4 acc[2][8];
#pragma unroll
  for (int m = 0; m < 2; ++m)
#pragma unroll
    for (int nf = 0; nf < 8; ++nf) acc[m][nf] = (f32x4)0.f;

  auto stage = [&](int buf, int k0) {
#pragma unroll
    for (int q = 0; q < 2; ++q) {
      gld16(xb + aOff[q] + k0, &As[buf][(w * 32 + q * 16) * 32]);
      gld16(WT + bOff[q] + k0, &Bs[buf][(w * 32 + q * 16) * 32]);
    }
  };

  stage(0, 0);
  __syncthreads();
  const int rslot = ((l >> 4) ^ ((l >> 1) & 3)) * 8;  // swizzled read slot (elems)
  const int arow = (w * 32 + (l & 15)) * 32 + rslot;
  for (int t = 0; t < HDIM / 32; ++t) {
    const int cur = t & 1;
    if (t + 1 < HDIM / 32) stage(cur ^ 1, (t + 1) * 32);
    const bf16x8 a0 = *(const bf16x8*)&As[cur][arow];
    const bf16x8 a1 = *(const bf16x8*)&As[cur][arow + 16 * 32];
#pragma unroll
    for (int nf = 0; nf < 8; ++nf) {
      const bf16x8 b = *(const bf16x8*)&Bs[cur][(nf * 16 + (l & 15)) * 32 + rslot];
      acc[0][nf] = __builtin_amdgcn_mfma_f32_16x16x32_bf16(a0, b, acc[0][nf], 0, 0, 0);
      acc[1][nf] = __builtin_amdgcn_mfma_f32_16x16x32_bf16(a1, b, acc[1][nf], 0, 0, 0);
    }
    __syncthreads();
  }
  const int rbase = m0 + w * 32 + (l >> 4) * 4;
  const int cbase = n0 + (l & 15);
#pragma unroll
  for (int m = 0; m < 2; ++m)
#pragma unroll
    for (int p = 0; p < 4; ++p) {
      const f32x4 up = acc[m][p];
      const f32x4 gt = acc[m][p + 4];
#pragma unroll
      for (int r = 0; r < 4; ++r) {
        const float u = up[r];
        const float s = (u / (1.f + expf(-u))) * gt[r];
        act[(size_t)(rbase + m * 16 + r) * IDIM + cbase + p * 16] = f2bf(s);
      }
    }
}

// grouped GEMM2: so[row][h] = act[row] @ W2T[e] (fp32 partials).
// Upgraded to gemm1's proven footprint: BM=128, BN=128, 4 waves,
// wave tile 32x128 (acc[2][8] = 64 VGPR), 16 MFMA : 10 ds_read, 32KB LDS.
__launch_bounds__(256, 2)
__global__ void k_gemm2(const unsigned short* __restrict__ act,
                        const unsigned short* __restrict__ W2T,
                        const int* __restrict__ seg,
                        float* __restrict__ so) {
  __shared__ __align__(16) unsigned short As[2][128 * 32];
  __shared__ __align__(16) unsigned short Bs[2][128 * 32];
  const int tid = threadIdx.x;
  const int w = tid >> 6, l = tid & 63;
  const int m0 = blockIdx.y * 128;
  const int total = seg[NEXP];
  if (m0 >= total) return;
  int e = 0;
#pragma unroll
  for (int q = 1; q < NEXP; ++q) if (m0 >= seg[q]) e = q;
  const int n0 = blockIdx.x * 128;
  const int swz = ((tid & 3) ^ ((tid >> 3) & 3)) * 8;  // staging source col (elems)
  size_t aOff[2], bOff[2];
#pragma unroll
  for (int q = 0; q < 2; ++q) {
    aOff[q] = (size_t)(m0 + q * 64 + (tid >> 2)) * IDIM + swz;
    bOff[q] = ((size_t)e * HDIM + n0 + q * 64 + (tid >> 2)) * IDIM + swz;
  }

  f32x4 acc[2][8];
#pragma unroll
  for (int mf = 0; mf < 2; ++mf)
#pragma unroll
    for (int nf = 0; nf < 8; ++nf) acc[mf][nf] = (f32x4)0.f;

  auto stage = [&](int buf, int k0) {
#pragma unroll
    for (int q = 0; q < 2; ++q) {
      gld16(act + aOff[q] + k0, &As[buf][(q * 64 + (tid >> 2)) * 32 + (tid & 3) * 8]);
      gld16(W2T + bOff[q] + k0, &Bs[buf][(q * 64 + (tid >> 2)) * 32 + (tid & 3) * 8]);
    }
  };

  stage(0, 0);
  __syncthreads();
  const int rslot = ((l >> 4) ^ ((l >> 1) & 3)) * 8;   // swizzled read slot (elems)
  const int arow = (w * 32 + (l & 15)) * 32 + rslot;
  for (int t = 0; t < IDIM / 32; ++t) {
    const int cur = t & 1;
    if (t + 1 < IDIM / 32) stage(cur ^ 1, (t + 1) * 32);
    const bf16x8 a0 = *(const bf16x8*)&As[cur][arow];
    const bf16x8 a1 = *(const bf16x8*)&As[cur][arow + 16 * 32];
#pragma unroll
    for (int nf = 0; nf < 8; ++nf) {
      const bf16x8 b = *(const bf16x8*)&Bs[cur][(nf * 16 + (l & 15)) * 32 + rslot];
      acc[0][nf] = __builtin_amdgcn_mfma_f32_16x16x32_bf16(a0, b, acc[0][nf], 0, 0, 0);
      acc[1][nf] = __builtin_amdgcn_mfma_f32_16x16x32_bf16(a1, b, acc[1][nf], 0, 0, 0);
    }
    __syncthreads();
  }
  const int rbase = m0 + w * 32 + (l >> 4) * 4;
  const int cbase = n0 + (l & 15);
#pragma unroll
  for (int mf = 0; mf < 2; ++mf)
#pragma unroll
    for (int nf = 0; nf < 8; ++nf)
#pragma unroll
      for (int r = 0; r < 4; ++r)
        so[(size_t)(rbase + mf * 16 + r) * HDIM + cbase + nf * 16] = acc[mf][nf][r];
}

__global__ void k_combine(const float* __restrict__ so, const int* __restrict__ pos,
                          const float* __restrict__ rw, float* __restrict__ out) {
  const int t = blockIdx.x, i = threadIdx.x;
  const int p0 = pos[2 * t], p1 = pos[2 * t + 1];
  const float w0 = rw[2 * t], w1 = rw[2 * t + 1];
  const float4 a = ((const float4*)(so + (size_t)p0 * HDIM))[i];
  const float4 b = ((const float4*)(so + (size_t)p1 * HDIM))[i];
  float4 o;
  o.x = w0 * a.x + w1 * b.x;
  o.y = w0 * a.y + w1 * b.y;
  o.z = w0 * a.z + w1 * b.z;
  o.w = w0 * a.w + w1 * b.w;
  ((float4*)(out + (size_t)t * HDIM))[i] = o;
}

extern "C" void kernel_launch(void* const* d_in, const int* in_sizes, int n_in,
                              void* d_out, int out_size, void* d_ws, size_t ws_size,
                              hipStream_t stream) {
  const float* x  = (const float*)d_in[0];
  const float* Wg = (const float*)d_in[1];
  const float* W1 = (const float*)d_in[2];
  const float* W2 = (const float*)d_in[3];   // (E, I, H)
  const float* W3 = (const float*)d_in[4];   // (E, H, I)
  float* out = (float*)d_out;
  char* ws = (char*)d_ws;
  int*   idx  = (int*)(ws + OFF_IDX);
  float* rw   = (float*)(ws + OFF_RW);
  int*   cnt  = (int*)(ws + OFF_CNT);
  int*   seg  = (int*)(ws + OFF_SEG);
  int*   rowsv= (int*)(ws + OFF_ROWS);
  int*   pos  = (int*)(ws + OFF_POS);
  unsigned short* xb  = (unsigned short*)(ws + OFF_XB);
  unsigned short* W1T = (unsigned short*)(ws + OFF_W1T);
  unsigned short* W3T = (unsigned short*)(ws + OFF_W3T);
  unsigned short* W2T = (unsigned short*)(ws + OFF_W2T);
  unsigned short* act = (unsigned short*)(ws + OFF_ACT);
  float* so = (float*)(ws + OFF_SO);

  k_init<<<20, 256, 0, stream>>>(cnt, rowsv);
  k_wtall<<<dim3(32, 32, 24), 256, 0, stream>>>(W1, W3, W2, W1T, W3T, W2T);
  k_router<<<NUM_TOK / 4, 256, 0, stream>>>(x, Wg, xb, idx, rw, cnt);
  k_seg<<<1, 1, 0, stream>>>(cnt, seg);
  k_scatter<<<NUM_TOK / 256, 256, 0, stream>>>(idx, seg, cnt + 8, rowsv, pos);
  k_gemm1<<<dim3(IDIM / 64, NTM), 256, 0, stream>>>(xb, W1T, W3T, seg, rowsv, act);
  k_gemm2<<<dim3(HDIM / 128, NTM), 256, 0, stream>>>(act, W2T, seg, so);
  k_combine<<<NUM_TOK, 256, 0, stream>>>(so, pos, rw, out);
}

// Round 6
// 245.558 us; speedup vs baseline: 1.1715x; 1.0278x over previous
//
#include <hip/hip_runtime.h>
#include <math.h>

#define NUM_TOK 2048
#define HDIM 1024
#define IDIM 2048
#define NEXP 8
#define MAX_ROWS 5120
#define NTM 40

typedef __attribute__((ext_vector_type(8))) short bf16x8;
typedef __attribute__((ext_vector_type(4))) float f32x4;

// ---- workspace offsets (bytes) ----
#define OFF_IDX   0u
#define OFF_RW    16384u
#define OFF_CNT   32768u
#define OFF_SEG   32832u
#define OFF_ROWS  33024u
#define OFF_POS   53504u
#define OFF_XB    131072u
#define OFF_W1T   8388608u
#define OFF_W3T   41943040u
#define OFF_W2T   75497472u
#define OFF_ACT   109051904u
#define OFF_SO    8388608u   /* aliases W1T (dead once gemm2 runs) */

__device__ __forceinline__ unsigned short f2bf(float f) {
  union { float f; unsigned u; } v; v.f = f;
  unsigned r = v.u + 0x7FFF + ((v.u >> 16) & 1);   // RNE
  return (unsigned short)(r >> 16);
}

__device__ __forceinline__ void gld16(const void* g, void* l) {
  __builtin_amdgcn_global_load_lds(
      (const __attribute__((address_space(1))) void*)g,
      (__attribute__((address_space(3))) void*)l, 16, 0, 0);
}

__global__ void k_init(int* __restrict__ cnt, int* __restrict__ rowsv) {
  const int i = blockIdx.x * blockDim.x + threadIdx.x;
  if (i < 16) cnt[i] = 0;
  if (i < MAX_ROWS) rowsv[i] = -1;
}

// fused transpose + fp32->bf16 for all three weights, conflict-free:
// dword-packed tile D[c][r2] (stride 33), bank = (c + r2) % 32 on writes,
// (c + 4m + j) % 32 on reads -> uniform 2-way (free) both phases.
// z 0..7: W1 (H,I)->(I,H); 8..15: W3; 16..23: W2 (I,H)->(H,I)
__global__ void k_wtall(const float* __restrict__ W1, const float* __restrict__ W3,
                        const float* __restrict__ W2,
                        unsigned short* __restrict__ W1T,
                        unsigned short* __restrict__ W3T,
                        unsigned short* __restrict__ W2T) {
  __shared__ unsigned D[64 * 33];
  const int z = blockIdx.z;
  const float* src; unsigned short* dst; int R, C, eidx;
  if (z < 8)       { src = W1; dst = W1T; R = HDIM; C = IDIM; eidx = z; }
  else if (z < 16) { src = W3; dst = W3T; R = HDIM; C = IDIM; eidx = z - 8; }
  else             { src = W2; dst = W2T; R = IDIM; C = HDIM; eidx = z - 16; }
  const int r0 = blockIdx.y * 64, c0 = blockIdx.x * 64;
  if (r0 >= R || c0 >= C) return;
  const int t = threadIdx.x;
  const size_t base = (size_t)eidx * R * C;
  const int c4 = (t & 15) * 4;
#pragma unroll
  for (int h = 0; h < 2; ++h) {
    const int r2 = (t >> 4) + h * 16;          // dword-row index 0..31
    const float4 v0 = *(const float4*)(src + base + (size_t)(r0 + 2 * r2) * C + c0 + c4);
    const float4 v1 = *(const float4*)(src + base + (size_t)(r0 + 2 * r2 + 1) * C + c0 + c4);
    const float a0[4] = {v0.x, v0.y, v0.z, v0.w};
    const float a1[4] = {v1.x, v1.y, v1.z, v1.w};
#pragma unroll
    for (int j = 0; j < 4; ++j)
      D[(c4 + j) * 33 + r2] = (unsigned)f2bf(a0[j]) | ((unsigned)f2bf(a1[j]) << 16);
  }
  __syncthreads();
  const int rq = (t & 7) * 4;                  // dword offset within a column
#pragma unroll
  for (int g = 0; g < 2; ++g) {
    const int c = (t >> 3) + g * 32;
    uint4 u;
    u.x = D[c * 33 + rq];
    u.y = D[c * 33 + rq + 1];
    u.z = D[c * 33 + rq + 2];
    u.w = D[c * 33 + rq + 3];
    *(uint4*)(dst + base + (size_t)(c0 + c) * R + r0 + rq * 2) = u;
  }
}

__global__ void k_router(const float* __restrict__ x, const float* __restrict__ wg,
                         unsigned short* __restrict__ xb,
                         int* __restrict__ idx, float* __restrict__ rw,
                         int* __restrict__ cnt) {
  const int wave = threadIdx.x >> 6, lane = threadIdx.x & 63;
  const int t = blockIdx.x * 4 + wave;
  const float2* __restrict__ xr = (const float2*)(x + (size_t)t * HDIM);
  unsigned* __restrict__ xbr = (unsigned*)(xb + (size_t)t * HDIM);
  float acc[8];
#pragma unroll
  for (int q = 0; q < 8; ++q) acc[q] = 0.f;
#pragma unroll
  for (int j = 0; j < 8; ++j) {
    const int h2 = lane + (j << 6);
    const float2 v = xr[h2];
    const float* wrow = wg + (size_t)h2 * 16;
    const float4 a0 = *(const float4*)(wrow);
    const float4 a1 = *(const float4*)(wrow + 4);
    const float4 b0 = *(const float4*)(wrow + 8);
    const float4 b1 = *(const float4*)(wrow + 12);
    acc[0] = fmaf(v.x, a0.x, fmaf(v.y, b0.x, acc[0]));
    acc[1] = fmaf(v.x, a0.y, fmaf(v.y, b0.y, acc[1]));
    acc[2] = fmaf(v.x, a0.z, fmaf(v.y, b0.z, acc[2]));
    acc[3] = fmaf(v.x, a0.w, fmaf(v.y, b0.w, acc[3]));
    acc[4] = fmaf(v.x, a1.x, fmaf(v.y, b1.x, acc[4]));
    acc[5] = fmaf(v.x, a1.y, fmaf(v.y, b1.y, acc[5]));
    acc[6] = fmaf(v.x, a1.z, fmaf(v.y, b1.z, acc[6]));
    acc[7] = fmaf(v.x, a1.w, fmaf(v.y, b1.w, acc[7]));
    xbr[h2] = (unsigned)f2bf(v.x) | ((unsigned)f2bf(v.y) << 16);
  }
#pragma unroll
  for (int q = 0; q < 8; ++q) {
#pragma unroll
    for (int off = 32; off >= 1; off >>= 1)
      acc[q] += __shfl_xor(acc[q], off, 64);
  }
  if (lane == 0) {
    int i0 = 0; float v0 = acc[0];
#pragma unroll
    for (int q = 1; q < 8; ++q)
      if (acc[q] > v0) { v0 = acc[q]; i0 = q; }
    int i1 = -1; float v1 = -3.4e38f;
#pragma unroll
    for (int q = 0; q < 8; ++q)
      if (q != i0 && acc[q] > v1) { v1 = acc[q]; i1 = q; }
    const float e1 = expf(v1 - v0);
    const float inv = 1.f / (1.f + e1);
    idx[2 * t] = i0; idx[2 * t + 1] = i1;
    rw[2 * t] = inv; rw[2 * t + 1] = e1 * inv;
    atomicAdd(&cnt[i0], 1);
    atomicAdd(&cnt[i1], 1);
  }
}

// single block: compute 128-aligned expert segments, then scatter slots
__global__ void k_segscatter(const int* __restrict__ cnt, int* __restrict__ seg,
                             int* __restrict__ cursor, const int* __restrict__ idx,
                             int* __restrict__ rowsv, int* __restrict__ pos) {
  __shared__ int sseg[NEXP];
  if (threadIdx.x == 0) {
    int s = 0;
    for (int q = 0; q < NEXP; ++q) {
      seg[q] = s; sseg[q] = s;
      s += ((cnt[q] + 127) / 128) * 128;
    }
    seg[NEXP] = s;
  }
  __syncthreads();
  for (int t = threadIdx.x; t < NUM_TOK; t += 256) {
#pragma unroll
    for (int k = 0; k < 2; ++k) {
      const int slot = 2 * t + k;
      const int e = idx[slot];
      const int p = atomicAdd(&cursor[e], 1);
      const int rr = sseg[e] + p;
      rowsv[rr] = slot;
      pos[slot] = rr;
    }
  }
}

// grouped GEMM1: act = silu(x@W1) * (x@W3); B-tile = 64 W1T rows + 64 W3T rows.
// (R3-proven config: BM=128, BN=64, 4 waves, wave tile 32x64+64, acc[2][8].)
__launch_bounds__(256, 2)
__global__ void k_gemm1(const unsigned short* __restrict__ xb,
                        const unsigned short* __restrict__ W1T,
                        const unsigned short* __restrict__ W3T,
                        const int* __restrict__ seg, const int* __restrict__ rowsv,
                        unsigned short* __restrict__ act) {
  __shared__ __align__(16) unsigned short As[2][128 * 32];
  __shared__ __align__(16) unsigned short Bs[2][128 * 32];
  const int tid = threadIdx.x;
  const int w = tid >> 6, l = tid & 63;
  const int m0 = blockIdx.y * 128;
  const int total = seg[NEXP];
  if (m0 >= total) return;
  int e = 0;
#pragma unroll
  for (int q = 1; q < NEXP; ++q) if (m0 >= seg[q]) e = q;
  const int n0 = blockIdx.x * 64;

  const int swzst = ((l & 3) ^ ((l >> 3) & 3)) * 8;   // staging source column (elems)
  size_t aOff[2], bOff[2];
#pragma unroll
  for (int q = 0; q < 2; ++q) {
    const int r = rowsv[m0 + w * 32 + q * 16 + (l >> 2)];
    const int tk = (r < 0) ? 0 : (r >> 1);
    aOff[q] = (size_t)tk * HDIM + swzst;
    bOff[q] = ((size_t)e * IDIM + n0 + (w & 1) * 32 + q * 16 + (l >> 2)) * HDIM + swzst;
  }
  const unsigned short* __restrict__ WT = (w < 2) ? W1T : W3T;

  f32x4 acc[2][8];
#pragma unroll
  for (int m = 0; m < 2; ++m)
#pragma unroll
    for (int nf = 0; nf < 8; ++nf) acc[m][nf] = (f32x4)0.f;

  auto stage = [&](int buf, int k0) {
#pragma unroll
    for (int q = 0; q < 2; ++q) {
      gld16(xb + aOff[q] + k0, &As[buf][(w * 32 + q * 16) * 32]);
      gld16(WT + bOff[q] + k0, &Bs[buf][(w * 32 + q * 16) * 32]);
    }
  };

  stage(0, 0);
  __syncthreads();
  const int rslot = ((l >> 4) ^ ((l >> 1) & 3)) * 8;  // swizzled read slot (elems)
  const int arow = (w * 32 + (l & 15)) * 32 + rslot;
  for (int t = 0; t < HDIM / 32; ++t) {
    const int cur = t & 1;
    if (t + 1 < HDIM / 32) stage(cur ^ 1, (t + 1) * 32);
    const bf16x8 a0 = *(const bf16x8*)&As[cur][arow];
    const bf16x8 a1 = *(const bf16x8*)&As[cur][arow + 16 * 32];
#pragma unroll
    for (int nf = 0; nf < 8; ++nf) {
      const bf16x8 b = *(const bf16x8*)&Bs[cur][(nf * 16 + (l & 15)) * 32 + rslot];
      acc[0][nf] = __builtin_amdgcn_mfma_f32_16x16x32_bf16(a0, b, acc[0][nf], 0, 0, 0);
      acc[1][nf] = __builtin_amdgcn_mfma_f32_16x16x32_bf16(a1, b, acc[1][nf], 0, 0, 0);
    }
    __syncthreads();
  }
  const int rbase = m0 + w * 32 + (l >> 4) * 4;
  const int cbase = n0 + (l & 15);
#pragma unroll
  for (int m = 0; m < 2; ++m)
#pragma unroll
    for (int p = 0; p < 4; ++p) {
      const f32x4 up = acc[m][p];
      const f32x4 gt = acc[m][p + 4];
#pragma unroll
      for (int r = 0; r < 4; ++r) {
        const float u = up[r];
        const float s = (u / (1.f + expf(-u))) * gt[r];
        act[(size_t)(rbase + m * 16 + r) * IDIM + cbase + p * 16] = f2bf(s);
      }
    }
}

// grouped GEMM2: so[row][h] = act[row] @ W2T[e] (fp32 partials).
// BM=128, BN=128, 4 waves, wave tile 32x128 (acc[2][8]), 16 MFMA : 10 ds_read.
__launch_bounds__(256, 2)
__global__ void k_gemm2(const unsigned short* __restrict__ act,
                        const unsigned short* __restrict__ W2T,
                        const int* __restrict__ seg,
                        float* __restrict__ so) {
  __shared__ __align__(16) unsigned short As[2][128 * 32];
  __shared__ __align__(16) unsigned short Bs[2][128 * 32];
  const int tid = threadIdx.x;
  const int w = tid >> 6, l = tid & 63;
  const int m0 = blockIdx.y * 128;
  const int total = seg[NEXP];
  if (m0 >= total) return;
  int e = 0;
#pragma unroll
  for (int q = 1; q < NEXP; ++q) if (m0 >= seg[q]) e = q;
  const int n0 = blockIdx.x * 128;
  const int swz = ((tid & 3) ^ ((tid >> 3) & 3)) * 8;  // staging source col (elems)
  size_t aOff[2], bOff[2];
#pragma unroll
  for (int q = 0; q < 2; ++q) {
    aOff[q] = (size_t)(m0 + q * 64 + (tid >> 2)) * IDIM + swz;
    bOff[q] = ((size_t)e * HDIM + n0 + q * 64 + (tid >> 2)) * IDIM + swz;
  }

  f32x4 acc[2][8];
#pragma unroll
  for (int mf = 0; mf < 2; ++mf)
#pragma unroll
    for (int nf = 0; nf < 8; ++nf) acc[mf][nf] = (f32x4)0.f;

  auto stage = [&](int buf, int k0) {
#pragma unroll
    for (int q = 0; q < 2; ++q) {
      gld16(act + aOff[q] + k0, &As[buf][(q * 64 + (tid >> 2)) * 32 + (tid & 3) * 8]);
      gld16(W2T + bOff[q] + k0, &Bs[buf][(q * 64 + (tid >> 2)) * 32 + (tid & 3) * 8]);
    }
  };

  stage(0, 0);
  __syncthreads();
  const int rslot = ((l >> 4) ^ ((l >> 1) & 3)) * 8;   // swizzled read slot (elems)
  const int arow = (w * 32 + (l & 15)) * 32 + rslot;
  for (int t = 0; t < IDIM / 32; ++t) {
    const int cur = t & 1;
    if (t + 1 < IDIM / 32) stage(cur ^ 1, (t + 1) * 32);
    const bf16x8 a0 = *(const bf16x8*)&As[cur][arow];
    const bf16x8 a1 = *(const bf16x8*)&As[cur][arow + 16 * 32];
#pragma unroll
    for (int nf = 0; nf < 8; ++nf) {
      const bf16x8 b = *(const bf16x8*)&Bs[cur][(nf * 16 + (l & 15)) * 32 + rslot];
      acc[0][nf] = __builtin_amdgcn_mfma_f32_16x16x32_bf16(a0, b, acc[0][nf], 0, 0, 0);
      acc[1][nf] = __builtin_amdgcn_mfma_f32_16x16x32_bf16(a1, b, acc[1][nf], 0, 0, 0);
    }
    __syncthreads();
  }
  const int rbase = m0 + w * 32 + (l >> 4) * 4;
  const int cbase = n0 + (l & 15);
#pragma unroll
  for (int mf = 0; mf < 2; ++mf)
#pragma unroll
    for (int nf = 0; nf < 8; ++nf)
#pragma unroll
      for (int r = 0; r < 4; ++r)
        so[(size_t)(rbase + mf * 16 + r) * HDIM + cbase + nf * 16] = acc[mf][nf][r];
}

__global__ void k_combine(const float* __restrict__ so, const int* __restrict__ pos,
                          const float* __restrict__ rw, float* __restrict__ out) {
  const int t = blockIdx.x, i = threadIdx.x;
  const int p0 = pos[2 * t], p1 = pos[2 * t + 1];
  const float w0 = rw[2 * t], w1 = rw[2 * t + 1];
  const float4 a = ((const float4*)(so + (size_t)p0 * HDIM))[i];
  const float4 b = ((const float4*)(so + (size_t)p1 * HDIM))[i];
  float4 o;
  o.x = w0 * a.x + w1 * b.x;
  o.y = w0 * a.y + w1 * b.y;
  o.z = w0 * a.z + w1 * b.z;
  o.w = w0 * a.w + w1 * b.w;
  ((float4*)(out + (size_t)t * HDIM))[i] = o;
}

extern "C" void kernel_launch(void* const* d_in, const int* in_sizes, int n_in,
                              void* d_out, int out_size, void* d_ws, size_t ws_size,
                              hipStream_t stream) {
  const float* x  = (const float*)d_in[0];
  const float* Wg = (const float*)d_in[1];
  const float* W1 = (const float*)d_in[2];
  const float* W2 = (const float*)d_in[3];   // (E, I, H)
  const float* W3 = (const float*)d_in[4];   // (E, H, I)
  float* out = (float*)d_out;
  char* ws = (char*)d_ws;
  int*   idx  = (int*)(ws + OFF_IDX);
  float* rw   = (float*)(ws + OFF_RW);
  int*   cnt  = (int*)(ws + OFF_CNT);
  int*   seg  = (int*)(ws + OFF_SEG);
  int*   rowsv= (int*)(ws + OFF_ROWS);
  int*   pos  = (int*)(ws + OFF_POS);
  unsigned short* xb  = (unsigned short*)(ws + OFF_XB);
  unsigned short* W1T = (unsigned short*)(ws + OFF_W1T);
  unsigned short* W3T = (unsigned short*)(ws + OFF_W3T);
  unsigned short* W2T = (unsigned short*)(ws + OFF_W2T);
  unsigned short* act = (unsigned short*)(ws + OFF_ACT);
  float* so = (float*)(ws + OFF_SO);

  k_init<<<20, 256, 0, stream>>>(cnt, rowsv);
  k_wtall<<<dim3(32, 32, 24), 256, 0, stream>>>(W1, W3, W2, W1T, W3T, W2T);
  k_router<<<NUM_TOK / 4, 256, 0, stream>>>(x, Wg, xb, idx, rw, cnt);
  k_segscatter<<<1, 256, 0, stream>>>(cnt, seg, cnt + 8, idx, rowsv, pos);
  k_gemm1<<<dim3(IDIM / 64, NTM), 256, 0, stream>>>(xb, W1T, W3T, seg, rowsv, act);
  k_gemm2<<<dim3(HDIM / 128, NTM), 256, 0, stream>>>(act, W2T, seg, so);
  k_combine<<<NUM_TOK, 256, 0, stream>>>(so, pos, rw, out);
}